// Round 4
// baseline (304.421 us; speedup 1.0000x reference)
//
#include <hip/hip_runtime.h>
#include <hip/hip_bf16.h>
#include <math.h>

typedef __hip_bfloat16 bf16;
typedef __attribute__((ext_vector_type(8))) short short8;
typedef __attribute__((ext_vector_type(4))) float floatx4;
#define DEV __device__ __forceinline__

constexpr int BATCH = 4;
constexpr int DIM   = 256;
constexpr int C2    = 128;
constexpr int GK    = 40;     // HEADS*KS = 8*5
constexpr int HH    = 128;
constexpr int WW    = 128;
constexpr int NPIX  = HH * WW;   // 16384
constexpr int TPB   = 256;

DEV float toF(float v) { return v; }
DEV float toF(bf16 v)  { return __bfloat162float(v); }

DEV unsigned short f2bs(float f) {
  union { bf16 h; unsigned short u; } cv;
  cv.h = __float2bfloat16(f);
  return cv.u;
}
DEV float bs2f(unsigned short u) {
  union { float f; unsigned x; } c;
  c.x = ((unsigned)u) << 16;
  return c.f;
}

template<int N>
DEV void load_f32v(const float* __restrict__ p, float* v) {
  if constexpr (N == 8) {
    const float4 a = *(const float4*)p;
    const float4 b = *(const float4*)(p + 4);
    v[0]=a.x; v[1]=a.y; v[2]=a.z; v[3]=a.w; v[4]=b.x; v[5]=b.y; v[6]=b.z; v[7]=b.w;
  } else if constexpr (N == 4) {
    const float4 a = *(const float4*)p;
    v[0]=a.x; v[1]=a.y; v[2]=a.z; v[3]=a.w;
  } else {
    const float2 a = *(const float2*)p;
    v[0]=a.x; v[1]=a.y;
  }
}
template<int N>
DEV void load_bf16v(const bf16* __restrict__ p, float* v) {
  if constexpr (N == 8) {
    const uint4 u = *(const uint4*)p;
    v[0]=bs2f(u.x & 0xffff); v[1]=bs2f(u.x >> 16);
    v[2]=bs2f(u.y & 0xffff); v[3]=bs2f(u.y >> 16);
    v[4]=bs2f(u.z & 0xffff); v[5]=bs2f(u.z >> 16);
    v[6]=bs2f(u.w & 0xffff); v[7]=bs2f(u.w >> 16);
  } else if constexpr (N == 4) {
    const uint2 u = *(const uint2*)p;
    v[0]=bs2f(u.x & 0xffff); v[1]=bs2f(u.x >> 16);
    v[2]=bs2f(u.y & 0xffff); v[3]=bs2f(u.y >> 16);
  } else {
    const unsigned u = *(const unsigned*)p;
    v[0]=bs2f(u & 0xffff); v[1]=bs2f(u >> 16);
  }
}
DEV void load8bf(const bf16* __restrict__ p, float* v) { load_bf16v<8>(p, v); }

// ==================== weight prepack: f32 -> bf16 =============================
__global__ __launch_bounds__(TPB) void prepack_kernel(
    const float* __restrict__ w0, const float* __restrict__ w1,
    const float* __restrict__ w2, const float* __restrict__ w3,
    const float* __restrict__ w4, const float* __restrict__ w5,
    short* __restrict__ dst) {
  const int i = blockIdx.x * TPB + threadIdx.x;
  if (i >= 157696) return;
  int j = i;
  float v;
  if (j < 65536) v = w0[j];
  else if ((j -= 65536) < 8192) v = w1[j];
  else if ((j -= 8192) < 8192) v = w2[j];
  else if ((j -= 8192) < 5120) v = w3[j];
  else if ((j -= 5120) < 5120) v = w4[j];
  else { j -= 5120; v = w5[j]; }
  dst[i] = (short)f2bs(v);
}

// ==================== MFMA pointwise conv v3 ====================
// GEMM per 64-px strip: out[o][px] = act(W[o][:]·in[:][px] + bias[o]).
// LDS B-tile layout: [k_oct = k/8][phys_px = px ^ (k_oct&7)] 16B words, no pad:
//   staging ds_write_b128 and fragment ds_read_b128 are both bank-even.
// Epilogue: acc -> wave-private LDS f32 tile [o_l][px], row stride 68 f32
//   (2-way write, even read) -> 16B coalesced global stores.
// MODE: 0 plain, 1 gated concat (proj_out), 2 fused horizontal 7-tap dw conv.
template<int K, int O, int ACT, int MODE, typename TIN, typename TOUT>
__global__ __launch_bounds__(TPB) void pw3_kernel(
    const TIN* __restrict__ in, int in_bs,
    const short* __restrict__ wbf, const float* __restrict__ bias,
    TOUT* __restrict__ out, int out_bs,
    const bf16* __restrict__ gxc, const bf16* __restrict__ gattn,
    const float* __restrict__ gs, const float* __restrict__ gc,
    const float* __restrict__ dww, const float* __restrict__ dwb) {
  constexpr int NO8 = K / 8;         // k-octets
  constexpr int PXT = K / 32;        // px per staging thread (8/4/2)
  constexpr int PG  = 2048 / K;      // threads per octet row
  constexpr int WO  = (O + 63) / 64; // 16-row o-tiles per wave
  constexpr int TBS = 16 * 68 * 4;   // 4352B transpose tile per wave
  constexpr int LDSB = (NO8 * 1024 > 4 * TBS) ? NO8 * 1024 : 4 * TBS;
  __shared__ char smem[LDSB];

  const int p0   = blockIdx.x * 64;
  const int b    = blockIdx.y;
  const int t    = threadIdx.x;
  const int lane = t & 63, wid = t >> 6;
  const int q    = lane >> 4, i16 = lane & 15;

  // ---------- stage 64px x K tile ----------
  {
    const int c8  = t / PG;
    const int px0 = (t % PG) * PXT;
    float vals[8][PXT];
    if constexpr (MODE == 1) {
      float svals[PXT];
      if (c8 < NO8 / 2) load_f32v<PXT>(gs + (size_t)b * NPIX + p0 + px0, svals);
#pragma unroll
      for (int j = 0; j < 8; ++j) {
        const int c = c8 * 8 + j;
        float tmp[PXT];
        if (c < C2) {
          load_bf16v<PXT>(gxc + ((size_t)b * C2 + c) * NPIX + p0 + px0, tmp);
#pragma unroll
          for (int i = 0; i < PXT; ++i) vals[j][i] = tmp[i] * svals[i];
        } else {
          const float cg = gc[b * C2 + (c - C2)];
          load_bf16v<PXT>(gattn + ((size_t)b * C2 + (c - C2)) * NPIX + p0 + px0, tmp);
#pragma unroll
          for (int i = 0; i < PXT; ++i) vals[j][i] = tmp[i] * cg;
        }
      }
    } else if constexpr (MODE == 2) {
      // fused depthwise 1x7 along W on bf16 input
      const int row   = p0 >> 7;           // whole 64-px strip is in one image row
      const int col_t = (p0 & (WW - 1)) + px0;
#pragma unroll
      for (int j = 0; j < 8; ++j) {
        const int c = c8 * 8 + j;
        const bf16* xr = (const bf16*)in + ((size_t)b * in_bs + c) * NPIX + row * WW;
        float w12[12];
        if (col_t >= 4) load_bf16v<4>(xr + col_t - 4, w12);
        else { w12[0]=w12[1]=w12[2]=w12[3]=0.f; }
        load_bf16v<4>(xr + col_t, w12 + 4);
        if (col_t <= WW - 8) load_bf16v<4>(xr + col_t + 4, w12 + 8);
        else { w12[8]=w12[9]=w12[10]=w12[11]=0.f; }
        float wv[7];
#pragma unroll
        for (int jj = 0; jj < 7; ++jj) wv[jj] = dww[c * 7 + jj];
        const float bv = dwb[c];
#pragma unroll
        for (int i = 0; i < PXT; ++i) {
          float a = bv;
#pragma unroll
          for (int jj = 0; jj < 7; ++jj) a = fmaf(wv[jj], w12[i + 1 + jj], a);
          vals[j][i] = a;
        }
      }
    } else {
#pragma unroll
      for (int j = 0; j < 8; ++j) {
        const int c = c8 * 8 + j;
        const TIN* src = in + ((size_t)b * in_bs + c) * NPIX + p0 + px0;
        float tmp[PXT];
        if constexpr (sizeof(TIN) == 4) load_f32v<PXT>((const float*)src, tmp);
        else                            load_bf16v<PXT>((const bf16*)src, tmp);
#pragma unroll
        for (int i = 0; i < PXT; ++i) vals[j][i] = tmp[i];
      }
    }
#pragma unroll
    for (int i = 0; i < PXT; ++i) {
      const int px = px0 + i;
      short8 pk;
#pragma unroll
      for (int j = 0; j < 8; ++j) pk[j] = (short)f2bs(vals[j][i]);
      const int phys = px ^ (c8 & 7);
      *reinterpret_cast<short8*>(smem + (size_t)(c8 * 64 + phys) * 16) = pk;
    }
  }
  __syncthreads();

  const int o_base = wid * WO * 16;
  const bool wave_active = (o_base < O);

  floatx4 acc[WO][4];
#pragma unroll
  for (int ot = 0; ot < WO; ++ot)
#pragma unroll
    for (int nt = 0; nt < 4; ++nt)
      acc[ot][nt] = (floatx4){0.f, 0.f, 0.f, 0.f};

  if (wave_active) {
    for (int kc = 0; kc < K / 32; ++kc) {
      short8 afrag[WO];
#pragma unroll
      for (int ot = 0; ot < WO; ++ot) {
        int o = o_base + ot * 16 + i16;
        if (o >= O) o = O - 1;          // clamp; masked at store
        afrag[ot] = *reinterpret_cast<const short8*>(wbf + (size_t)o * K + kc * 32 + q * 8);
      }
      const int k_oct = kc * 4 + q;
      short8 bfrag[4];
#pragma unroll
      for (int nt = 0; nt < 4; ++nt) {
        const int phys = (nt * 16 + i16) ^ (k_oct & 7);
        bfrag[nt] = *reinterpret_cast<const short8*>(smem + (size_t)(k_oct * 64 + phys) * 16);
      }
#pragma unroll
      for (int ot = 0; ot < WO; ++ot)
#pragma unroll
        for (int nt = 0; nt < 4; ++nt)
          acc[ot][nt] = __builtin_amdgcn_mfma_f32_16x16x32_bf16(
              afrag[ot], bfrag[nt], acc[ot][nt], 0, 0, 0);
    }
  }

  __syncthreads();                      // B-tile dead; reuse smem for transpose
  float* tb = reinterpret_cast<float*>(smem + wid * TBS);

  if (!wave_active) return;             // no barriers below; regions wave-private
#pragma unroll
  for (int ot = 0; ot < WO; ++ot) {
    // ---- write phase: C/D layout col=lane&15 (px), row=q*4+reg (o) ----
#pragma unroll
    for (int reg = 0; reg < 4; ++reg) {
      const int o = o_base + ot * 16 + q * 4 + reg;
      const float bv = (o < O) ? bias[o] : 0.f;
#pragma unroll
      for (int nt = 0; nt < 4; ++nt) {
        float v = acc[ot][nt][reg] + bv;
        if (ACT == 1) v = fmaxf(v, 0.0f);
        if (ACT == 2) v = tanhf(v);
        tb[(q * 4 + reg) * 68 + nt * 16 + i16] = v;
      }
    }
    // ---- read phase (intra-wave, compiler-inserted lgkmcnt) ----
    if constexpr (sizeof(TOUT) == 4) {
#pragma unroll
      for (int s = 0; s < 4; ++s) {
        const int o_l  = lane >> 2;
        const int quad = (lane & 3) + 4 * s;
        const int o    = o_base + ot * 16 + o_l;
        const float4 v = *reinterpret_cast<const float4*>(tb + o_l * 68 + quad * 4);
        if (o < O)
          *reinterpret_cast<float4*>((float*)out + ((size_t)b * out_bs + o) * NPIX + p0 + quad * 4) = v;
      }
    } else {
#pragma unroll
      for (int s = 0; s < 2; ++s) {
        const int o_l = lane >> 2;
        const int px8 = (lane & 3) + 4 * s;
        const int o   = o_base + ot * 16 + o_l;
        const float4 lo = *reinterpret_cast<const float4*>(tb + o_l * 68 + px8 * 8);
        const float4 hi = *reinterpret_cast<const float4*>(tb + o_l * 68 + px8 * 8 + 4);
        short8 pk;
        pk[0]=(short)f2bs(lo.x); pk[1]=(short)f2bs(lo.y);
        pk[2]=(short)f2bs(lo.z); pk[3]=(short)f2bs(lo.w);
        pk[4]=(short)f2bs(hi.x); pk[5]=(short)f2bs(hi.y);
        pk[6]=(short)f2bs(hi.z); pk[7]=(short)f2bs(hi.w);
        if (o < O)
          *reinterpret_cast<short8*>((bf16*)out + ((size_t)b * out_bs + o) * NPIX + p0 + px8 * 8) = pk;
      }
    }
  }
}

// ==================== depthwise 7x1 along H (bf16 in), 8 px/thread ===========
__global__ __launch_bounds__(TPB) void dwv2_kernel(
    const bf16* __restrict__ in,
    const float* __restrict__ w7, const float* __restrict__ bias,
    bf16* __restrict__ out) {
  const int g  = blockIdx.x * TPB + threadIdx.x;
  const int w8 = g & 15;
  const int hp = (g >> 4) & (HH - 1);
  const int c  = (g >> 11) & (C2 - 1);
  const int b  = g >> 18;
  const int px0 = w8 * 8;
  const bf16* base = in + ((size_t)(b * C2 + c)) * NPIX + px0;
  float r[7][8];
#pragma unroll
  for (int j = 0; j < 7; ++j) {
    const int hq = hp - 3 + j;
    if (hq >= 0 && hq < HH) load8bf(base + (size_t)hq * WW, r[j]);
    else
#pragma unroll
      for (int i = 0; i < 8; ++i) r[j][i] = 0.f;
  }
  float wv[7];
#pragma unroll
  for (int j = 0; j < 7; ++j) wv[j] = w7[c * 7 + j];
  const float bv = bias[c];
  short8 o;
#pragma unroll
  for (int i = 0; i < 8; ++i) {
    float a = bv;
#pragma unroll
    for (int j = 0; j < 7; ++j) a = fmaf(wv[j], r[j][i], a);
    o[i] = (short)f2bs(a);
  }
  *reinterpret_cast<short8*>(out + ((size_t)(b * C2 + c)) * NPIX + hp * WW + px0) = o;
}

// ==================== FSA horizontal (bf16 x2 + kern), 8 px/thread ===========
__global__ __launch_bounds__(TPB) void fsah3_kernel(
    const bf16* __restrict__ x, int x_bs,
    const bf16* __restrict__ kern, bf16* __restrict__ out) {
  const int g  = blockIdx.x * TPB + threadIdx.x;
  const int w8 = g & 15;
  const int hp = (g >> 4) & (HH - 1);
  const int c  = (g >> 11) & (C2 - 1);
  const int b  = g >> 18;
  const bf16* xr = x + ((size_t)b * x_bs + c) * NPIX + hp * WW;
  const int px0 = w8 * 8;
  float xs[14];                         // cols px0-3 .. px0+10
  if (w8 > 0) { float t4[4]; load_bf16v<4>(xr + px0 - 4, t4); xs[0]=t4[1]; xs[1]=t4[2]; xs[2]=t4[3]; }
  else { xs[0]=xs[1]=xs[2]=0.f; }
  load_bf16v<8>(xr + px0, xs + 3);
  if (w8 < 15) { float t4[4]; load_bf16v<4>(xr + px0 + 8, t4); xs[11]=t4[0]; xs[12]=t4[1]; xs[13]=t4[2]; }
  else { xs[11]=xs[12]=xs[13]=0.f; }
  float k[5][8];
  const bf16* kr = kern + ((size_t)b * GK + (c >> 4) * 5) * NPIX + hp * WW + px0;
#pragma unroll
  for (int tp = 0; tp < 5; ++tp) load8bf(kr + (size_t)tp * NPIX, k[tp]);
  short8 o;
#pragma unroll
  for (int i = 0; i < 8; ++i) {
    float a = 0.5f * (xs[i] + xs[i + 1]) * k[0][i];
    a = fmaf(xs[i + 2], k[1][i], a);
    a = fmaf(xs[i + 3], k[2][i], a);
    a = fmaf(xs[i + 4], k[3][i], a);
    a = fmaf(0.5f * (xs[i + 5] + xs[i + 6]), k[4][i], a);
    o[i] = (short)f2bs(a);
  }
  *reinterpret_cast<short8*>(out + ((size_t)(b * C2 + c)) * NPIX + hp * WW + px0) = o;
}

// ==================== FSA vertical (bf16 in + kern), 8 px/thread =============
__global__ __launch_bounds__(TPB) void fsav2_kernel(
    const bf16* __restrict__ x,
    const bf16* __restrict__ kern, bf16* __restrict__ out) {
  const int g  = blockIdx.x * TPB + threadIdx.x;
  const int w8 = g & 15;
  const int hp = (g >> 4) & (HH - 1);
  const int c  = (g >> 11) & (C2 - 1);
  const int b  = g >> 18;
  const int px0 = w8 * 8;
  const bf16* base = x + ((size_t)(b * C2 + c)) * NPIX + px0;
  float r[7][8];
#pragma unroll
  for (int j = 0; j < 7; ++j) {
    const int hq = hp - 3 + j;
    if (hq >= 0 && hq < HH) load8bf(base + (size_t)hq * WW, r[j]);
    else
#pragma unroll
      for (int i = 0; i < 8; ++i) r[j][i] = 0.f;
  }
  float k[5][8];
  const bf16* kr = kern + ((size_t)b * GK + (c >> 4) * 5) * NPIX + hp * WW + px0;
#pragma unroll
  for (int tp = 0; tp < 5; ++tp) load8bf(kr + (size_t)tp * NPIX, k[tp]);
  short8 o;
#pragma unroll
  for (int i = 0; i < 8; ++i) {
    float a = 0.5f * (r[0][i] + r[1][i]) * k[0][i];
    a = fmaf(r[2][i], k[1][i], a);
    a = fmaf(r[3][i], k[2][i], a);
    a = fmaf(r[4][i], k[3][i], a);
    a = fmaf(0.5f * (r[5][i] + r[6][i]), k[4][i], a);
    o[i] = (short)f2bs(a);
  }
  *reinterpret_cast<short8*>(out + ((size_t)(b * C2 + c)) * NPIX + hp * WW + px0) = o;
}

// -------------------- block reduction (result valid in thread 0)
DEV float block_reduce_sum(float v) {
#pragma unroll
  for (int off = 32; off > 0; off >>= 1) v += __shfl_down(v, off, 64);
  __shared__ float ls[TPB / 64];
  const int lane = threadIdx.x & 63;
  const int wid  = threadIdx.x >> 6;
  if (lane == 0) ls[wid] = v;
  __syncthreads();
  float s = 0.0f;
  if (threadIdx.x == 0) {
#pragma unroll
    for (int i = 0; i < TPB / 64; ++i) s += ls[i];
  }
  return s;
}

__global__ __launch_bounds__(TPB) void mean_n_kernel(const bf16* __restrict__ in,
                                                     float* __restrict__ out) {
  const int bc = blockIdx.x;
  const bf16* r = in + (size_t)bc * NPIX;
  float s = 0.0f;
  for (int i = threadIdx.x * 8; i < NPIX; i += TPB * 8) {
    float v[8];
    load8bf(r + i, v);
#pragma unroll
    for (int j = 0; j < 8; ++j) s += v[j];
  }
  s = block_reduce_sum(s);
  if (threadIdx.x == 0) out[bc] = s * (1.0f / NPIX);
}

// fused xc_mean + s_sig: one channel-scan of x_conv per (b,px)
__global__ __launch_bounds__(TPB) void colscan_kernel(const bf16* __restrict__ xc,
                                                      const float* __restrict__ at_mean,
                                                      float* __restrict__ xc_mean,
                                                      float* __restrict__ s_sig) {
  __shared__ float am[C2];
  const int b = blockIdx.y;
  if (threadIdx.x < C2) am[threadIdx.x] = at_mean[b * C2 + threadIdx.x];
  __syncthreads();
  const int p = blockIdx.x * TPB + threadIdx.x;
  const bf16* r = xc + (size_t)b * C2 * NPIX + p;
  float s1 = 0.0f, s2 = 0.0f;
#pragma unroll 4
  for (int c = 0; c < C2; ++c) {
    const float v = toF(r[(size_t)c * NPIX]);
    s1 += v;
    s2 = fmaf(am[c], v, s2);
  }
  xc_mean[(size_t)b * NPIX + p] = s1 * (1.0f / C2);
  s_sig[(size_t)b * NPIX + p]   = 1.0f / (1.0f + expf(-s2 * (1.0f / C2)));
}

__global__ __launch_bounds__(TPB) void csig_kernel(const bf16* __restrict__ attn,
                                                   const float* __restrict__ xc_mean,
                                                   float* __restrict__ out) {
  const int bc = blockIdx.x;
  const int b  = bc / C2;
  const bf16* r = attn + (size_t)bc * NPIX;
  const float* m = xc_mean + (size_t)b * NPIX;
  float s = 0.0f;
  for (int i = threadIdx.x * 8; i < NPIX; i += TPB * 8) {
    float v[8], mm[8];
    load8bf(r + i, v);
    load_f32v<8>(m + i, mm);
#pragma unroll
    for (int j = 0; j < 8; ++j) s = fmaf(v[j], mm[j], s);
  }
  s = block_reduce_sum(s);
  if (threadIdx.x == 0) out[bc] = 1.0f / (1.0f + expf(-s * (1.0f / NPIX)));
}

extern "C" void kernel_launch(void* const* d_in, const int* in_sizes, int n_in,
                              void* d_out, int out_size, void* d_ws, size_t ws_size,
                              hipStream_t stream) {
  const float* x    = (const float*)d_in[0];
  const float* piw  = (const float*)d_in[1];
  const float* pib  = (const float*)d_in[2];
  const float* hkdw = (const float*)d_in[3];
  const float* hkdb = (const float*)d_in[4];
  const float* hkpw = (const float*)d_in[5];
  const float* hkpb = (const float*)d_in[6];
  const float* vkdw = (const float*)d_in[7];
  const float* vkdb = (const float*)d_in[8];
  const float* vkpw = (const float*)d_in[9];
  const float* vkpb = (const float*)d_in[10];
  const float* cbw1 = (const float*)d_in[11];
  const float* cbb1 = (const float*)d_in[12];
  const float* cbw2 = (const float*)d_in[13];
  const float* cbb2 = (const float*)d_in[14];
  const float* pow_ = (const float*)d_in[15];
  const float* pob  = (const float*)d_in[16];
  float* out = (float*)d_out;

  char* ws = (char*)d_ws;
  size_t off = 0;
  auto alloc = [&](size_t bytes) -> char* {
    char* p = ws + off;
    off += (bytes + 255) & ~(size_t)255;
    return p;
  };
  short* wpk    = (short*)alloc(157696 * 2);                       // packed bf16 weights
  bf16*  h      = (bf16*) alloc((size_t)BATCH * DIM * NPIX * 2);   // bf16 now
  bf16*  t1     = (bf16*) alloc((size_t)BATCH * 64  * NPIX * 2);
  bf16*  x_conv = (bf16*) alloc((size_t)BATCH * C2  * NPIX * 2);
  bf16*  dwbuf  = (bf16*) alloc((size_t)BATCH * C2  * NPIX * 2);
  bf16*  kbuf   = (bf16*) alloc((size_t)BATCH * GK  * NPIX * 2);
  bf16*  attn_h = (bf16*) alloc((size_t)BATCH * C2  * NPIX * 2);
  bf16*  attn   = (bf16*) alloc((size_t)BATCH * C2  * NPIX * 2);
  float* at_mean = (float*)alloc((size_t)BATCH * C2 * 4);
  float* xc_mean = (float*)alloc((size_t)BATCH * NPIX * 4);
  float* s_sig   = (float*)alloc((size_t)BATCH * NPIX * 4);
  float* c_sig   = (float*)alloc((size_t)BATCH * C2 * 4);

  const short* w_pi  = wpk;
  const short* w_cb1 = wpk + 65536;
  const short* w_cb2 = wpk + 73728;
  const short* w_hk  = wpk + 81920;
  const short* w_vk  = wpk + 87040;
  const short* w_po  = wpk + 92160;

  const dim3 blk(TPB);
  const dim3 gemm_grid(NPIX / 64, BATCH);
  const int PT  = NPIX / TPB;
  const int EL8 = BATCH * C2 * NPIX / (TPB * 8);   // 4096
  const bf16* x2 = h + (size_t)C2 * NPIX;          // channels 128.. (batch stride DIM)

  // 0. prepack weights -> bf16
  prepack_kernel<<<dim3((157696 + TPB - 1) / TPB), blk, 0, stream>>>(
      piw, cbw1, cbw2, hkpw, vkpw, pow_, wpk);
  // 1. h = proj_in(x)            K=256 O=256, bf16 out
  pw3_kernel<256, 256, 0, 0, float, bf16><<<gemm_grid, blk, 0, stream>>>(
      x, DIM, w_pi, pib, h, DIM, nullptr, nullptr, nullptr, nullptr, nullptr, nullptr);
  // 2. t1 = relu(cb1(x1))        K=128 O=64
  pw3_kernel<128, 64, 1, 0, bf16, bf16><<<gemm_grid, blk, 0, stream>>>(
      h, DIM, w_cb1, cbb1, t1, 64, nullptr, nullptr, nullptr, nullptr, nullptr, nullptr);
  // 3. x_conv = cb2(t1)          K=64 O=128
  pw3_kernel<64, 128, 0, 0, bf16, bf16><<<gemm_grid, blk, 0, stream>>>(
      t1, 64, w_cb2, cbb2, x_conv, C2, nullptr, nullptr, nullptr, nullptr, nullptr, nullptr);
  // 4. kh = tanh(hk_pw(dw_h(x2)))  K=128 O=40, dwh fused into staging
  pw3_kernel<128, 40, 2, 2, bf16, bf16><<<gemm_grid, blk, 0, stream>>>(
      x2, DIM, w_hk, hkpb, kbuf, GK, nullptr, nullptr, nullptr, nullptr, hkdw, hkdb);
  // 5. attn_h = fsa_h(x2, kh)
  fsah3_kernel<<<dim3(EL8), blk, 0, stream>>>(x2, DIM, kbuf, attn_h);
  // 6. dwbuf = dw_v(attn_h)
  dwv2_kernel<<<dim3(EL8), blk, 0, stream>>>(attn_h, vkdw, vkdb, dwbuf);
  // 7. kv = tanh(vk_pw(dwbuf))   K=128 O=40
  pw3_kernel<128, 40, 2, 0, bf16, bf16><<<gemm_grid, blk, 0, stream>>>(
      dwbuf, C2, w_vk, vkpb, kbuf, GK, nullptr, nullptr, nullptr, nullptr, nullptr, nullptr);
  // 8. attn = fsa_v(attn_h, kv)
  fsav2_kernel<<<dim3(EL8), blk, 0, stream>>>(attn_h, kbuf, attn);
  // 9-11. gating
  mean_n_kernel<<<dim3(BATCH * C2), blk, 0, stream>>>(attn, at_mean);
  colscan_kernel<<<dim3(PT, BATCH), blk, 0, stream>>>(x_conv, at_mean, xc_mean, s_sig);
  csig_kernel<<<dim3(BATCH * C2), blk, 0, stream>>>(attn, xc_mean, c_sig);
  // 12. out = proj_out([s_sig*xc ; c_sig*attn])  — concat fused into staging
  pw3_kernel<256, 256, 0, 1, bf16, float><<<gemm_grid, blk, 0, stream>>>(
      x_conv, 0, w_po, pob, out, DIM, x_conv, attn, s_sig, c_sig, nullptr, nullptr);
}